// Round 7
// baseline (284.129 us; speedup 1.0000x reference)
//
#include <hip/hip_runtime.h>
#include <cstddef>
#include <cstdint>

// z: (8, 256, 16,16,16) fp32; embedding: (1024, 256) fp32
#define CDIM 256
#define SPAT 4096
#define KCODE 1024

#define LOSS_OFF 8388608
#define PERP_OFF 8388609
#define IDX_OFF  8388610

typedef __bf16 bf16x8 __attribute__((ext_vector_type(8)));
typedef float floatx16 __attribute__((ext_vector_type(16)));
typedef unsigned short us8 __attribute__((ext_vector_type(8)));

__device__ __forceinline__ unsigned short f2bf_rne(float f) {
    union { float f; uint32_t u; } c; c.f = f;
    uint32_t u = c.u;
    return (unsigned short)((u + 0x7fffu + ((u >> 16) & 1u)) >> 16);
}
__device__ __forceinline__ float bf2f(unsigned short h) {
    union { float f; uint32_t u; } c; c.u = ((uint32_t)h) << 16;
    return c.f;
}

// async global->LDS, 16B per lane; lds dest = uniform base + lane*16
__device__ __forceinline__ void dma16(const void* g, void* l) {
    __builtin_amdgcn_global_load_lds(
        (const __attribute__((address_space(1))) void*)g,
        (__attribute__((address_space(3))) void*)l, 16, 0, 0);
}

// ---------------------------------------------------------------------------
// Prep: split embedding into bf16 hi/lo in the kb-major stage layout:
//   code k -> kh=k>>9, s=(k>>5)&15, ks=k&31
//   ushort index = (s*2+kh)*8192 + kb*256 + ks*8 + (c&7),  kb = c>>3
// A-reads in vq_main are then 32 consecutive 16B chunks -> conflict-free.
// Also enorm (exact R1 reduction order) and zero counts/losssum.
// ---------------------------------------------------------------------------
__global__ __launch_bounds__(256) void vq_prep(const float* __restrict__ emb,
                                               unsigned short* __restrict__ ehsw,
                                               unsigned short* __restrict__ elsw,
                                               float* __restrict__ enorm,
                                               float* __restrict__ counts,
                                               float* __restrict__ losssum) {
    int tid = threadIdx.x;
    if (blockIdx.x == 0) {
        for (int i = tid; i < KCODE; i += 256) counts[i] = 0.0f;
        if (tid == 0) losssum[0] = 0.0f;
    }
    int w = tid >> 6, lane = tid & 63;
    int k = blockIdx.x * 4 + w;
    const float* row = emb + (size_t)k * CDIM;
    float s = 0.0f;
#pragma unroll
    for (int i = 0; i < 4; ++i) {
        float v = row[lane + 64 * i];
        s = fmaf(v, v, s);
    }
#pragma unroll
    for (int m = 32; m > 0; m >>= 1) s += __shfl_xor(s, m, 64);
    if (lane == 0) enorm[k] = s;

    float4 v4 = *(const float4*)(row + lane * 4);
    unsigned short h0 = f2bf_rne(v4.x), h1 = f2bf_rne(v4.y),
                   h2 = f2bf_rne(v4.z), h3 = f2bf_rne(v4.w);
    ushort4 hv = make_ushort4(h0, h1, h2, h3);
    ushort4 lv = make_ushort4(f2bf_rne(v4.x - bf2f(h0)), f2bf_rne(v4.y - bf2f(h1)),
                              f2bf_rne(v4.z - bf2f(h2)), f2bf_rne(v4.w - bf2f(h3)));
    int kb = lane >> 1, cj = (lane & 1) * 4;
    int kh = k >> 9, st = (k >> 5) & 15, ks = k & 31;
    size_t dst = (size_t)(st * 2 + kh) * 8192 + kb * 256 + ks * 8 + cj;
    *(ushort4*)(ehsw + dst) = hv;
    *(ushort4*)(elsw + dst) = lv;
}

// ---------------------------------------------------------------------------
// Main: bf16x3 MFMA distance GEMM, producer/consumer parity waves.
// grid 256 x 512 threads (8 waves): par=w>>2, kh=(w>>1)&1, cw=w&1.
// Wave: cols cw*64..+64 (2 reg N-tiles), codes kh*512..+512, stages s≡par.
// Interval s: par==s&1 waves compute stage s (buf s&1); others DMA s+1.
// Each wave consumes the bytes it DMA'd itself (vmcnt drained at its own
// barrier crossing). Stage = 64 KB (2 kh x 32 codes x hi+lo), dbuf 128 KB.
// d = fp32(zz+ee) - 2*M replicates np's rounding structure exactly.
// ---------------------------------------------------------------------------
__global__ __launch_bounds__(512, 2) void vq_main(const float* __restrict__ z,
                                                  const float* __restrict__ emb,
                                                  const unsigned short* __restrict__ ehsw,
                                                  const unsigned short* __restrict__ elsw,
                                                  const float* __restrict__ enorm,
                                                  float* __restrict__ counts,
                                                  float* __restrict__ losssum,
                                                  float* __restrict__ out) {
    __shared__ __align__(16) unsigned char lds[131072 + 4096 + 512 + 2048 + 2048 + 512];
    float* zhalf = (float*)lds;                       // phase1 overlay on buf0
    float* ens_s = (float*)(lds + 131072);            // 1024 f
    float* zzs   = (float*)(lds + 135168);            // 128 f
    float* pb_s  = (float*)(lds + 135680);            // [4][128]
    int*   pb_i  = (int*)(lds + 137728);              // [4][128]
    int*   bidxs = (int*)(lds + 139776);              // 128 i

    const int tid = threadIdx.x;
    const int w = tid >> 6;
    const int lane = tid & 63;
    const int m_ = lane & 31;
    const int g = lane >> 5;
    const int par = w >> 2;            // stage parity this wave computes
    const int kh = (w >> 1) & 1;       // code half (512 codes)
    const int cw = w & 1;              // column half (64 cols)
    const int n0 = blockIdx.x * 128;
    const int b = n0 >> 12;
    const int sp0 = n0 & 4095;
    const float* zb = z + (size_t)b * CDIM * SPAT + sp0;

    us8 zh0[16], zl0[16], zh1[16], zl1[16];

    // ---- phase 1: two 64-col halves ----
    for (int h = 0; h < 2; ++h) {
        for (int i = tid; i < CDIM * 16; i += 512) {
            int c = i >> 4, seg = i & 15;
            *(float4*)&zhalf[c * 64 + seg * 4] =
                *(const float4*)(zb + (size_t)c * SPAT + h * 64 + seg * 4);
        }
        __syncthreads();
        if (cw == h) {
            // all 4 waves of this column half extract identical frags
#pragma unroll
            for (int t = 0; t < 2; ++t) {
#pragma unroll
                for (int kc = 0; kc < 16; ++kc) {
#pragma unroll
                    for (int j = 0; j < 8; ++j) {
                        float v = zhalf[(kc * 16 + g * 8 + j) * 64 + t * 32 + m_];
                        unsigned short hb = f2bf_rne(v);
                        unsigned short lb = f2bf_rne(v - bf2f(hb));
                        if (t == 0) { zh0[kc][j] = hb; zl0[kc][j] = lb; }
                        else        { zh1[kc][j] = hb; zl1[kc][j] = lb; }
                    }
                }
            }
        } else if (kh == 0 && par == 0) {
            // zz per column (R1-exact sequential fmaf order)
            float s = 0.0f;
            for (int c = 0; c < CDIM; ++c) {
                float v = zhalf[c * 64 + lane];
                s = fmaf(v, v, s);
            }
            zzs[h * 64 + lane] = s;
        } else if (kh == 1 && par == 0 && h == 0) {
            for (int i = lane; i < KCODE; i += 64) ens_s[i] = enorm[i];
        }
        __syncthreads();
    }

    const float zzv0 = zzs[cw * 64 + m_];
    const float zzv1 = zzs[cw * 64 + 32 + m_];

    float bs0 = 3.4e38f, bs1 = 3.4e38f;
    int bi0 = 0, bi1 = 0;

    // wave's DMA role: (kh, cw): cw=0 -> eh slice, cw=1 -> el slice (16 KB)
    const char* gsrc = (const char*)(cw ? elsw : ehsw);

    // ---- prologue: par-0 waves DMA stage 0 into buf 0 ----
    if (par == 0) {
        const char* gp = gsrc + ((size_t)kh << 14) + (lane << 4);
        char* lp = (char*)lds + ((size_t)kh << 15) + ((size_t)cw << 14);
#pragma unroll
        for (int j = 0; j < 16; ++j) dma16(gp + j * 1024, lp + j * 1024);
    }

    // ---- main loop: 16 stages; compute / DMA alternate by parity ----
    for (int s = 0; s < 16; ++s) {
        __syncthreads();
        if ((s & 1) == par) {
            // compute stage s from buf (s&1)
            const char* EHb = (const char*)lds + (((size_t)s & 1) << 16) + ((size_t)kh << 15);
            const char* ELb = EHb + 16384;

            floatx16 a0 = {0.0f, 0.0f, 0.0f, 0.0f, 0.0f, 0.0f, 0.0f, 0.0f,
                           0.0f, 0.0f, 0.0f, 0.0f, 0.0f, 0.0f, 0.0f, 0.0f};
            floatx16 a1 = a0;
#pragma unroll
            for (int kc = 0; kc < 16; ++kc) {
                int kb0 = kc * 2 + g;
                int off = kb0 * 512 + m_ * 16;     // contiguous: conflict-free
                bf16x8 aeh = *(const bf16x8*)(EHb + off);
                bf16x8 ael = *(const bf16x8*)(ELb + off);
                bf16x8 bh0 = __builtin_bit_cast(bf16x8, zh0[kc]);
                bf16x8 bl0 = __builtin_bit_cast(bf16x8, zl0[kc]);
                bf16x8 bh1 = __builtin_bit_cast(bf16x8, zh1[kc]);
                bf16x8 bl1 = __builtin_bit_cast(bf16x8, zl1[kc]);
                a0 = __builtin_amdgcn_mfma_f32_32x32x16_bf16(aeh, bh0, a0, 0, 0, 0);
                a1 = __builtin_amdgcn_mfma_f32_32x32x16_bf16(aeh, bh1, a1, 0, 0, 0);
                a0 = __builtin_amdgcn_mfma_f32_32x32x16_bf16(ael, bh0, a0, 0, 0, 0);
                a1 = __builtin_amdgcn_mfma_f32_32x32x16_bf16(ael, bh1, a1, 0, 0, 0);
                a0 = __builtin_amdgcn_mfma_f32_32x32x16_bf16(aeh, bl0, a0, 0, 0, 0);
                a1 = __builtin_amdgcn_mfma_f32_32x32x16_bf16(aeh, bl1, a1, 0, 0, 0);
            }
            // epilogue: ascending code order per lane; strict < keeps lowest
#pragma unroll
            for (int reg = 0; reg < 16; ++reg) {
                int mm = (reg & 3) + 8 * (reg >> 2) + 4 * g;
                int code = kh * 512 + s * 32 + mm;
                float en = ens_s[code];
                float d0 = (zzv0 + en) - 2.0f * a0[reg];
                float d1 = (zzv1 + en) - 2.0f * a1[reg];
                if (d0 < bs0) { bs0 = d0; bi0 = code; }
                if (d1 < bs1) { bs1 = d1; bi1 = code; }
            }
        } else if (s < 15) {
            // DMA stage s+1 into buf ((s+1)&1) — consumed by THIS wave next
            const char* gp = gsrc + ((size_t)((s + 1) * 2 + kh) << 14) + (lane << 4);
            char* lp = (char*)lds + (((size_t)(s + 1) & 1) << 16)
                       + ((size_t)kh << 15) + ((size_t)cw << 14);
#pragma unroll
            for (int j = 0; j < 16; ++j) dma16(gp + j * 1024, lp + j * 1024);
        }
    }

    // ---- merge g-halves (disjoint code subsets), tie -> low index ----
    {
        float s2 = __shfl_xor(bs0, 32, 64);
        int i2 = __shfl_xor(bi0, 32, 64);
        if (s2 < bs0 || (s2 == bs0 && i2 < bi0)) { bs0 = s2; bi0 = i2; }
        float s3 = __shfl_xor(bs1, 32, 64);
        int i3 = __shfl_xor(bi1, 32, 64);
        if (s3 < bs1 || (s3 == bs1 && i3 < bi1)) { bs1 = s3; bi1 = i3; }
    }
    __syncthreads();
    if (lane < 32) {
        int r = par * 2 + kh;
        pb_s[r * 128 + cw * 64 + m_] = bs0;
        pb_s[r * 128 + cw * 64 + 32 + m_] = bs1;
        pb_i[r * 128 + cw * 64 + m_] = bi0;
        pb_i[r * 128 + cw * 64 + 32 + m_] = bi1;
    }
    __syncthreads();
    if (tid < 128) {
        float s = pb_s[tid];
        int ki = pb_i[tid];
#pragma unroll
        for (int r = 1; r < 4; ++r) {
            float s2 = pb_s[r * 128 + tid];
            int k2 = pb_i[r * 128 + tid];
            if (s2 < s || (s2 == s && k2 < ki)) { s = s2; ki = k2; }
        }
        bidxs[tid] = ki;
        out[IDX_OFF + n0 + tid] = (float)ki;
        atomicAdd(&counts[ki], 1.0f);
    }
    __syncthreads();

    // ---- gather z_q, STE output zp + (q - zp), loss (bidx cached in regs) ----
    float ls = 0.0f;
    float* outz = out + (size_t)b * CDIM * SPAT + sp0;
    const int col4 = tid & 31;         // this thread's 4 columns
    const int c_0 = tid >> 5;          // starting c, stride 16
    int k0 = bidxs[col4 * 4 + 0];
    int k1 = bidxs[col4 * 4 + 1];
    int k2 = bidxs[col4 * 4 + 2];
    int k3 = bidxs[col4 * 4 + 3];
    const float* e0 = emb + (size_t)k0 * CDIM;
    const float* e1 = emb + (size_t)k1 * CDIM;
    const float* e2 = emb + (size_t)k2 * CDIM;
    const float* e3 = emb + (size_t)k3 * CDIM;
    for (int c = c_0; c < CDIM; c += 16) {
        float4 zp = *(const float4*)(zb + (size_t)c * SPAT + col4 * 4);
        float d0 = e0[c] - zp.x, d1 = e1[c] - zp.y,
              d2 = e2[c] - zp.z, d3 = e3[c] - zp.w;
        float4 o;
        o.x = zp.x + d0; o.y = zp.y + d1; o.z = zp.z + d2; o.w = zp.w + d3;
        ls = fmaf(d0, d0, ls); ls = fmaf(d1, d1, ls);
        ls = fmaf(d2, d2, ls); ls = fmaf(d3, d3, ls);
        *(float4*)(outz + (size_t)c * SPAT + col4 * 4) = o;
    }
#pragma unroll
    for (int m = 32; m > 0; m >>= 1) ls += __shfl_xor(ls, m, 64);
    if (lane == 0) atomicAdd(losssum, ls);
}

// ---------------------------------------------------------------------------
// loss + perplexity
// ---------------------------------------------------------------------------
__global__ __launch_bounds__(256) void vq_finalize(const float* __restrict__ counts,
                                                   const float* __restrict__ losssum,
                                                   float* __restrict__ out) {
    __shared__ float red[256];
    int tid = threadIdx.x;
    float s = 0.0f;
    for (int k = tid; k < KCODE; k += 256) {
        float em = counts[k] * (1.0f / 32768.0f);
        s += em * logf(em + 1e-10f);
    }
    red[tid] = s;
    __syncthreads();
    for (int off = 128; off > 0; off >>= 1) {
        if (tid < off) red[tid] += red[tid + off];
        __syncthreads();
    }
    if (tid == 0) {
        float m = losssum[0] * (1.0f / 8388608.0f);
        out[LOSS_OFF] = m + 0.25f * m;
        out[PERP_OFF] = expf(-red[0]);
    }
}

extern "C" void kernel_launch(void* const* d_in, const int* in_sizes, int n_in,
                              void* d_out, int out_size, void* d_ws, size_t ws_size,
                              hipStream_t stream) {
    const float* z = (const float*)d_in[0];
    const float* emb = (const float*)d_in[1];
    float* out = (float*)d_out;
    unsigned short* ehsw = (unsigned short*)d_ws;            // 1024*256 ushort (staged layout)
    unsigned short* elsw = ehsw + (size_t)KCODE * CDIM;      // 1024*256 ushort
    float* enorm = (float*)(elsw + (size_t)KCODE * CDIM);    // 1024 f
    float* counts = enorm + KCODE;                           // 1024 f
    float* losssum = counts + KCODE;                         // 1 f

    vq_prep<<<256, 256, 0, stream>>>(emb, ehsw, elsw, enorm, counts, losssum);
    vq_main<<<256, 512, 0, stream>>>(z, emb, ehsw, elsw, enorm, counts, losssum, out);
    vq_finalize<<<1, 256, 0, stream>>>(counts, losssum, out);
}

// Round 8
// 216.801 us; speedup vs baseline: 1.3106x; 1.3106x over previous
//
#include <hip/hip_runtime.h>
#include <cstddef>
#include <cstdint>

// z: (8, 256, 16,16,16) fp32; embedding: (1024, 256) fp32
#define CDIM 256
#define SPAT 4096
#define KCODE 1024

#define LOSS_OFF 8388608
#define PERP_OFF 8388609
#define IDX_OFF  8388610

typedef __bf16 bf16x8 __attribute__((ext_vector_type(8)));
typedef float floatx16 __attribute__((ext_vector_type(16)));
typedef unsigned short us8 __attribute__((ext_vector_type(8)));

__device__ __forceinline__ unsigned short f2bf_rne(float f) {
    union { float f; uint32_t u; } c; c.f = f;
    uint32_t u = c.u;
    return (unsigned short)((u + 0x7fffu + ((u >> 16) & 1u)) >> 16);
}
__device__ __forceinline__ float bf2f(unsigned short h) {
    union { float f; uint32_t u; } c; c.u = ((uint32_t)h) << 16;
    return c.f;
}

// ---------------------------------------------------------------------------
// Prep: split embedding into bf16 hi/lo in the MFMA-fragment-major table:
//   code k -> kh=k>>9, cb=(k>>5)&15, m=k&31 ; c -> kc=c>>4, g=(c>>3)&1, c&7
//   ushort idx = ((kh*16+cb)*16+kc)*512 + (g*32+m)*8 + (c&7)
// vq_main's A-loads are then 1 KB contiguous per wave instruction (lane-major).
// Also enorm (exact R1 reduction order) and zero counts/losssum.
// ---------------------------------------------------------------------------
__global__ __launch_bounds__(256) void vq_prep(const float* __restrict__ emb,
                                               unsigned short* __restrict__ eht,
                                               unsigned short* __restrict__ elt,
                                               float* __restrict__ enorm,
                                               float* __restrict__ counts,
                                               float* __restrict__ losssum) {
    int tid = threadIdx.x;
    if (blockIdx.x == 0) {
        for (int i = tid; i < KCODE; i += 256) counts[i] = 0.0f;
        if (tid == 0) losssum[0] = 0.0f;
    }
    int w = tid >> 6, lane = tid & 63;
    int k = blockIdx.x * 4 + w;
    const float* row = emb + (size_t)k * CDIM;
    float s = 0.0f;
#pragma unroll
    for (int i = 0; i < 4; ++i) {
        float v = row[lane + 64 * i];
        s = fmaf(v, v, s);
    }
#pragma unroll
    for (int m = 32; m > 0; m >>= 1) s += __shfl_xor(s, m, 64);
    if (lane == 0) enorm[k] = s;

    float4 v4 = *(const float4*)(row + lane * 4);   // c = lane*4 .. +3
    unsigned short h0 = f2bf_rne(v4.x), h1 = f2bf_rne(v4.y),
                   h2 = f2bf_rne(v4.z), h3 = f2bf_rne(v4.w);
    ushort4 hv = make_ushort4(h0, h1, h2, h3);
    ushort4 lv = make_ushort4(f2bf_rne(v4.x - bf2f(h0)), f2bf_rne(v4.y - bf2f(h1)),
                              f2bf_rne(v4.z - bf2f(h2)), f2bf_rne(v4.w - bf2f(h3)));
    int kc = lane >> 2;
    int g = (lane >> 1) & 1;
    int cj = (lane & 1) * 4;
    int m_ = k & 31, cb = (k >> 5) & 15, kh = k >> 9;
    size_t dst = (size_t)(((kh * 16 + cb) * 16 + kc)) * 512 + (g * 32 + m_) * 8 + cj;
    *(ushort4*)(eht + dst) = hv;
    *(ushort4*)(elt + dst) = lv;
}

// ---------------------------------------------------------------------------
// Main: bf16x3 MFMA distance GEMM with A streamed GLOBAL->REG (no K-loop LDS,
// no K-loop barriers). 256 blocks x 256 threads (4 waves = kh(2) x cw(2)),
// 128 cols/block; wave: cols cw*64..+64 in registers, codes kh*512..+512.
// LDS holds the full 128-col z tile (128 KB) for phase-1 + epilogue.
// d = fp32(zz+ee) - 2*M replicates np's rounding structure exactly.
// ---------------------------------------------------------------------------
__global__ __launch_bounds__(256, 1) void vq_main(const float* __restrict__ z,
                                                  const float* __restrict__ emb,
                                                  const unsigned short* __restrict__ eht,
                                                  const unsigned short* __restrict__ elt,
                                                  const float* __restrict__ enorm,
                                                  float* __restrict__ counts,
                                                  float* __restrict__ losssum,
                                                  float* __restrict__ out) {
    __shared__ __align__(16) unsigned char lds[131072 + 4096 + 512 + 1024 + 1024 + 512];
    float* zt    = (float*)lds;                       // [2][256][64] fp32, 128 KB
    float* ens_s = (float*)(lds + 131072);            // 1024 f
    float* zzs   = (float*)(lds + 135168);            // 128 f
    float* pb_s  = (float*)(lds + 135680);            // [2][128]
    int*   pb_i  = (int*)(lds + 136704);              // [2][128]
    int*   bidxs = (int*)(lds + 137728);              // 128 i

    const int tid = threadIdx.x;
    const int w = tid >> 6;
    const int lane = tid & 63;
    const int m_ = lane & 31;
    const int g = lane >> 5;
    const int kh = w >> 1;             // code half (512 codes)
    const int cw = w & 1;              // column half (64 cols)
    const int n0 = blockIdx.x * 128;
    const int b = n0 >> 12;
    const int sp0 = n0 & 4095;
    const float* zb = z + (size_t)b * CDIM * SPAT + sp0;

    us8 zh0[16], zl0[16], zh1[16], zl1[16];

    // ---- phase 1: stage both 64-col halves into LDS; zz; extract B frags ----
    for (int h = 0; h < 2; ++h) {
        float* zhalf = zt + h * 16384;
        for (int i = tid; i < CDIM * 16; i += 256) {
            int c = i >> 4, seg = i & 15;
            *(float4*)&zhalf[c * 64 + seg * 4] =
                *(const float4*)(zb + (size_t)c * SPAT + h * 64 + seg * 4);
        }
        __syncthreads();
        if (cw == h) {
            // both kh waves of this column half extract identical frags
#pragma unroll
            for (int t = 0; t < 2; ++t) {
#pragma unroll
                for (int kc = 0; kc < 16; ++kc) {
#pragma unroll
                    for (int j = 0; j < 8; ++j) {
                        float v = zhalf[(kc * 16 + g * 8 + j) * 64 + t * 32 + m_];
                        unsigned short hb = f2bf_rne(v);
                        unsigned short lb = f2bf_rne(v - bf2f(hb));
                        if (t == 0) { zh0[kc][j] = hb; zl0[kc][j] = lb; }
                        else        { zh1[kc][j] = hb; zl1[kc][j] = lb; }
                    }
                }
            }
        } else if (kh == 0) {
            // zz per column (R1-exact sequential fmaf order)
            float s = 0.0f;
            for (int c = 0; c < CDIM; ++c) {
                float v = zhalf[c * 64 + lane];
                s = fmaf(v, v, s);
            }
            zzs[h * 64 + lane] = s;
        } else if (h == 0) {
            for (int i = lane; i < KCODE; i += 64) ens_s[i] = enorm[i];
        }
        __syncthreads();
    }

    const float zzv0 = zzs[cw * 64 + m_];
    const float zzv1 = zzs[cw * 64 + 32 + m_];

    float bs0 = 3.4e38f, bs1 = 3.4e38f;
    int bi0 = 0, bi1 = 0;

    // A streamed from global: per (cb,kc) one 1 KB coalesced b128 per plane
    const us8* Ah = (const us8*)eht + ((size_t)kh << 14) + lane;
    const us8* Al = (const us8*)elt + ((size_t)kh << 14) + lane;

    for (int cb = 0; cb < 16; ++cb) {
        floatx16 a0 = {0.0f, 0.0f, 0.0f, 0.0f, 0.0f, 0.0f, 0.0f, 0.0f,
                       0.0f, 0.0f, 0.0f, 0.0f, 0.0f, 0.0f, 0.0f, 0.0f};
        floatx16 a1 = a0;
#pragma unroll
        for (int kc = 0; kc < 16; ++kc) {
            us8 ehu = Ah[(cb * 16 + kc) * 64];
            us8 elu = Al[(cb * 16 + kc) * 64];
            bf16x8 aeh = __builtin_bit_cast(bf16x8, ehu);
            bf16x8 ael = __builtin_bit_cast(bf16x8, elu);
            bf16x8 bh0 = __builtin_bit_cast(bf16x8, zh0[kc]);
            bf16x8 bl0 = __builtin_bit_cast(bf16x8, zl0[kc]);
            bf16x8 bh1 = __builtin_bit_cast(bf16x8, zh1[kc]);
            bf16x8 bl1 = __builtin_bit_cast(bf16x8, zl1[kc]);
            a0 = __builtin_amdgcn_mfma_f32_32x32x16_bf16(aeh, bh0, a0, 0, 0, 0);
            a1 = __builtin_amdgcn_mfma_f32_32x32x16_bf16(aeh, bh1, a1, 0, 0, 0);
            a0 = __builtin_amdgcn_mfma_f32_32x32x16_bf16(ael, bh0, a0, 0, 0, 0);
            a1 = __builtin_amdgcn_mfma_f32_32x32x16_bf16(ael, bh1, a1, 0, 0, 0);
            a0 = __builtin_amdgcn_mfma_f32_32x32x16_bf16(aeh, bl0, a0, 0, 0, 0);
            a1 = __builtin_amdgcn_mfma_f32_32x32x16_bf16(aeh, bl1, a1, 0, 0, 0);
        }
        // epilogue: ascending code order per lane; strict < keeps lowest idx
#pragma unroll
        for (int reg = 0; reg < 16; ++reg) {
            int mm = (reg & 3) + 8 * (reg >> 2) + 4 * g;
            int code = kh * 512 + cb * 32 + mm;
            float en = ens_s[code];
            float d0 = (zzv0 + en) - 2.0f * a0[reg];
            float d1 = (zzv1 + en) - 2.0f * a1[reg];
            if (d0 < bs0) { bs0 = d0; bi0 = code; }
            if (d1 < bs1) { bs1 = d1; bi1 = code; }
        }
    }

    // ---- merge g-halves (disjoint code subsets), tie -> low index ----
    {
        float s2 = __shfl_xor(bs0, 32, 64);
        int i2 = __shfl_xor(bi0, 32, 64);
        if (s2 < bs0 || (s2 == bs0 && i2 < bi0)) { bs0 = s2; bi0 = i2; }
        float s3 = __shfl_xor(bs1, 32, 64);
        int i3 = __shfl_xor(bi1, 32, 64);
        if (s3 < bs1 || (s3 == bs1 && i3 < bi1)) { bs1 = s3; bi1 = i3; }
    }
    __syncthreads();
    if (lane < 32) {
        pb_s[kh * 128 + cw * 64 + m_] = bs0;
        pb_s[kh * 128 + cw * 64 + 32 + m_] = bs1;
        pb_i[kh * 128 + cw * 64 + m_] = bi0;
        pb_i[kh * 128 + cw * 64 + 32 + m_] = bi1;
    }
    __syncthreads();
    if (tid < 128) {
        float s = pb_s[tid];
        int ki = pb_i[tid];
        float s2 = pb_s[128 + tid];
        int k2 = pb_i[128 + tid];
        if (s2 < s || (s2 == s && k2 < ki)) { s = s2; ki = k2; }
        bidxs[tid] = ki;
        out[IDX_OFF + n0 + tid] = (float)ki;
        atomicAdd(&counts[ki], 1.0f);
    }
    __syncthreads();

    // ---- gather z_q from LDS z-tile, STE out zp + (q - zp), loss partial ----
    float ls = 0.0f;
    float* outz = out + (size_t)b * CDIM * SPAT + sp0;
    const int col4 = tid & 31;          // global col group: cols col4*4..+3
    const int c_0 = tid >> 5;           // starting c, stride 8
    const int hh = col4 >> 4;           // which 64-col half in zt
    const int lc = (col4 & 15) * 4;     // local col within half
    int k0 = bidxs[col4 * 4 + 0];
    int k1 = bidxs[col4 * 4 + 1];
    int k2 = bidxs[col4 * 4 + 2];
    int k3 = bidxs[col4 * 4 + 3];
    const float* e0 = emb + (size_t)k0 * CDIM;
    const float* e1 = emb + (size_t)k1 * CDIM;
    const float* e2 = emb + (size_t)k2 * CDIM;
    const float* e3 = emb + (size_t)k3 * CDIM;
    for (int c = c_0; c < CDIM; c += 8) {
        float4 zp = *(const float4*)&zt[hh * 16384 + c * 64 + lc];
        float d0 = e0[c] - zp.x, d1 = e1[c] - zp.y,
              d2 = e2[c] - zp.z, d3 = e3[c] - zp.w;
        float4 o;
        o.x = zp.x + d0; o.y = zp.y + d1; o.z = zp.z + d2; o.w = zp.w + d3;
        ls = fmaf(d0, d0, ls); ls = fmaf(d1, d1, ls);
        ls = fmaf(d2, d2, ls); ls = fmaf(d3, d3, ls);
        *(float4*)(outz + (size_t)c * SPAT + col4 * 4) = o;
    }
#pragma unroll
    for (int m = 32; m > 0; m >>= 1) ls += __shfl_xor(ls, m, 64);
    if (lane == 0) atomicAdd(losssum, ls);
}

// ---------------------------------------------------------------------------
// loss + perplexity
// ---------------------------------------------------------------------------
__global__ __launch_bounds__(256) void vq_finalize(const float* __restrict__ counts,
                                                   const float* __restrict__ losssum,
                                                   float* __restrict__ out) {
    __shared__ float red[256];
    int tid = threadIdx.x;
    float s = 0.0f;
    for (int k = tid; k < KCODE; k += 256) {
        float em = counts[k] * (1.0f / 32768.0f);
        s += em * logf(em + 1e-10f);
    }
    red[tid] = s;
    __syncthreads();
    for (int off = 128; off > 0; off >>= 1) {
        if (tid < off) red[tid] += red[tid + off];
        __syncthreads();
    }
    if (tid == 0) {
        float m = losssum[0] * (1.0f / 8388608.0f);
        out[LOSS_OFF] = m + 0.25f * m;
        out[PERP_OFF] = expf(-red[0]);
    }
}

extern "C" void kernel_launch(void* const* d_in, const int* in_sizes, int n_in,
                              void* d_out, int out_size, void* d_ws, size_t ws_size,
                              hipStream_t stream) {
    const float* z = (const float*)d_in[0];
    const float* emb = (const float*)d_in[1];
    float* out = (float*)d_out;
    unsigned short* eht = (unsigned short*)d_ws;             // 1024*256 ushort (frag-major)
    unsigned short* elt = eht + (size_t)KCODE * CDIM;        // 1024*256 ushort
    float* enorm = (float*)(elt + (size_t)KCODE * CDIM);     // 1024 f
    float* counts = enorm + KCODE;                           // 1024 f
    float* losssum = counts + KCODE;                         // 1 f

    vq_prep<<<256, 256, 0, stream>>>(emb, eht, elt, enorm, counts, losssum);
    vq_main<<<256, 256, 0, stream>>>(z, emb, eht, elt, enorm, counts, losssum, out);
    vq_finalize<<<1, 256, 0, stream>>>(counts, losssum, out);
}